// Round 1
// baseline (300.511 us; speedup 1.0000x reference)
//
#include <hip/hip_runtime.h>

// ---------------------------------------------------------------------------
// DistillationLoss: chamfer(student,teacher_points) + chamfer(student,gt)
//                 + edge loss + laplacian smooth + normal-consistency loss
// N=M=P=G=8192, F=16384. All fp32. Output: 1 float scalar.
//
// Dominant cost: 5 row-min passes over 8192x8192 pairwise distances.
// fp32 vector (no fp32 MFMA on CDNA4; bf16 a2+b2-2ab cancels badly).
// ---------------------------------------------------------------------------

__device__ __forceinline__ float wave_reduce_sum(float v) {
#pragma unroll
  for (int o = 32; o > 0; o >>= 1) v += __shfl_down(v, o, 64);
  return v;
}

__device__ __forceinline__ float dist2f(float ax, float ay, float az,
                                        const float* __restrict__ B, int j) {
  float dx = ax - B[3 * j + 0];
  float dy = ay - B[3 * j + 1];
  float dz = az - B[3 * j + 2];
  return fmaf(dx, dx, fmaf(dy, dy, dz * dz));
}

// Initialize workspace: min64 = all-ones (max), min-bits arrays = +inf bits,
// zero region (nbr_sum, deg, accumulators).
__global__ void init_ws_kernel(unsigned long long* __restrict__ min64, int n64,
                               unsigned* __restrict__ minbits, int nmin,
                               float* __restrict__ zr, int nz) {
  const int stride = gridDim.x * blockDim.x;
  const int t0 = blockIdx.x * blockDim.x + threadIdx.x;
  for (int i = t0; i < n64; i += stride) min64[i] = ~0ull;
  for (int i = t0; i < nmin; i += stride) minbits[i] = 0x7f800000u;  // +inf
  for (int i = t0; i < nz; i += stride) zr[i] = 0.0f;
}

// For each row i of A (nA x 3): min over B[j0:j1] of squared distance.
// atomicMin on float bits (valid: d2 >= 0 so uint order == float order).
__global__ void rowmin_kernel(const float* __restrict__ A, int nA,
                              const float* __restrict__ B, int nB,
                              int jChunk, unsigned* __restrict__ outBits) {
  const int i = blockIdx.x * blockDim.x + threadIdx.x;
  const bool act = (i < nA);
  float ax = 0.f, ay = 0.f, az = 0.f;
  if (act) { ax = A[3 * i]; ay = A[3 * i + 1]; az = A[3 * i + 2]; }
  const int j0 = blockIdx.y * jChunk;
  const int j1 = min(j0 + jChunk, nB);
  const float INF = __int_as_float(0x7f800000);
  float m0 = INF, m1 = INF, m2 = INF, m3 = INF;  // 4 accs: break fmin dep chain
  int j = j0;
  for (; j + 4 <= j1; j += 4) {
    float d0 = dist2f(ax, ay, az, B, j + 0);
    float d1 = dist2f(ax, ay, az, B, j + 1);
    float d2 = dist2f(ax, ay, az, B, j + 2);
    float d3 = dist2f(ax, ay, az, B, j + 3);
    m0 = fminf(m0, d0);
    m1 = fminf(m1, d1);
    m2 = fminf(m2, d2);
    m3 = fminf(m3, d3);
  }
  for (; j < j1; ++j) m0 = fminf(m0, dist2f(ax, ay, az, B, j));
  float mv = fminf(fminf(m0, m1), fminf(m2, m3));
  if (act) atomicMin(outBits + i, __float_as_uint(mv));
}

// Same, but tracks argmin. Packed (d2_bits<<32)|j so atomicMin(u64) gives
// min-d2 with smallest-index tie-break (matches jnp.argmin first-occurrence).
__global__ void rowargmin_kernel(const float* __restrict__ A, int nA,
                                 const float* __restrict__ B, int nB,
                                 int jChunk,
                                 unsigned long long* __restrict__ out64) {
  const int i = blockIdx.x * blockDim.x + threadIdx.x;
  const bool act = (i < nA);
  float ax = 0.f, ay = 0.f, az = 0.f;
  if (act) { ax = A[3 * i]; ay = A[3 * i + 1]; az = A[3 * i + 2]; }
  const int j0 = blockIdx.y * jChunk;
  const int j1 = min(j0 + jChunk, nB);
  const float INF = __int_as_float(0x7f800000);
  float m0 = INF, m1 = INF, m2 = INF, m3 = INF;
  int i0 = j0, i1 = j0, i2 = j0, i3 = j0;
  int j = j0;
  for (; j + 4 <= j1; j += 4) {
    float d0 = dist2f(ax, ay, az, B, j + 0);
    float d1 = dist2f(ax, ay, az, B, j + 1);
    float d2 = dist2f(ax, ay, az, B, j + 2);
    float d3 = dist2f(ax, ay, az, B, j + 3);
    if (d0 < m0) { m0 = d0; i0 = j + 0; }
    if (d1 < m1) { m1 = d1; i1 = j + 1; }
    if (d2 < m2) { m2 = d2; i2 = j + 2; }
    if (d3 < m3) { m3 = d3; i3 = j + 3; }
  }
  for (; j < j1; ++j) {
    float d = dist2f(ax, ay, az, B, j);
    if (d < m0) { m0 = d; i0 = j; }
  }
  unsigned long long p0 = ((unsigned long long)__float_as_uint(m0) << 32) | (unsigned)i0;
  unsigned long long p1 = ((unsigned long long)__float_as_uint(m1) << 32) | (unsigned)i1;
  unsigned long long p2 = ((unsigned long long)__float_as_uint(m2) << 32) | (unsigned)i2;
  unsigned long long p3 = ((unsigned long long)__float_as_uint(m3) << 32) | (unsigned)i3;
  unsigned long long b01 = (p0 < p1) ? p0 : p1;
  unsigned long long b23 = (p2 < p3) ? p2 : p3;
  unsigned long long best = (b01 < b23) ? b01 : b23;
  if (act) atomicMin(out64 + i, best);
}

// One thread per edge (3F edges from faces). Accumulates:
//  - sum of squared edge lengths -> acc[4]
//  - laplacian neighbor sums (both directions) -> nbr, deg
__global__ void edge_kernel(const int* __restrict__ fc, int f,
                            const float* __restrict__ v,
                            float* __restrict__ nbr, float* __restrict__ deg,
                            float* __restrict__ acc) {
  const int e = blockIdx.x * blockDim.x + threadIdx.x;
  const int nE = 3 * f;
  float es = 0.f;
  if (e < nE) {
    int a, b;
    if (e < f) { a = fc[3 * e + 0]; b = fc[3 * e + 1]; }
    else if (e < 2 * f) { int t = e - f; a = fc[3 * t + 1]; b = fc[3 * t + 2]; }
    else { int t = e - 2 * f; a = fc[3 * t + 2]; b = fc[3 * t + 0]; }
    float axv = v[3 * a], ayv = v[3 * a + 1], azv = v[3 * a + 2];
    float bxv = v[3 * b], byv = v[3 * b + 1], bzv = v[3 * b + 2];
    float dx = axv - bxv, dy = ayv - byv, dz = azv - bzv;
    es = fmaf(dx, dx, fmaf(dy, dy, dz * dz));
    atomicAdd(&nbr[3 * a + 0], bxv);
    atomicAdd(&nbr[3 * a + 1], byv);
    atomicAdd(&nbr[3 * a + 2], bzv);
    atomicAdd(&nbr[3 * b + 0], axv);
    atomicAdd(&nbr[3 * b + 1], ayv);
    atomicAdd(&nbr[3 * b + 2], azv);
    atomicAdd(&deg[a], 1.0f);
    atomicAdd(&deg[b], 1.0f);
  }
  es = wave_reduce_sum(es);
  if ((threadIdx.x & 63) == 0) atomicAdd(&acc[4], es);
}

// Per vertex: || nbr_sum/max(deg,1) - v || summed -> acc[5]
__global__ void smooth_kernel(const float* __restrict__ v,
                              const float* __restrict__ nbr,
                              const float* __restrict__ deg, int n,
                              float* __restrict__ acc) {
  const int i = blockIdx.x * blockDim.x + threadIdx.x;
  float s = 0.f;
  if (i < n) {
    float d = fmaxf(deg[i], 1.0f);
    float lx = nbr[3 * i + 0] / d - v[3 * i + 0];
    float ly = nbr[3 * i + 1] / d - v[3 * i + 1];
    float lz = nbr[3 * i + 2] / d - v[3 * i + 2];
    s = sqrtf(fmaf(lx, lx, fmaf(ly, ly, lz * lz)));
  }
  s = wave_reduce_sum(s);
  if ((threadIdx.x & 63) == 0) atomicAdd(&acc[5], s);
}

// Per student vertex: cosine(student_normal, teacher_normal[nearest]) -> acc[6]
__global__ void normal_kernel(const float* __restrict__ sn,
                              const float* __restrict__ tn,
                              const unsigned long long* __restrict__ min64,
                              int n, float* __restrict__ acc) {
  const int i = blockIdx.x * blockDim.x + threadIdx.x;
  float s = 0.f;
  if (i < n) {
    int idx = (int)(min64[i] & 0xffffffffull);
    float sx = sn[3 * i], sy = sn[3 * i + 1], sz = sn[3 * i + 2];
    float tx = tn[3 * idx], ty = tn[3 * idx + 1], tz = tn[3 * idx + 2];
    float num = fmaf(sx, tx, fmaf(sy, ty, sz * tz));
    float ns = sqrtf(fmaf(sx, sx, fmaf(sy, sy, sz * sz)));
    float nt = sqrtf(fmaf(tx, tx, fmaf(ty, ty, tz * tz)));
    float den = fmaxf(ns, 1e-8f) * fmaxf(nt, 1e-8f);
    s = num / den;
  }
  s = wave_reduce_sum(s);
  if ((threadIdx.x & 63) == 0) atomicAdd(&acc[6], s);
}

// Sum of sqrt(min_d2) per segment (4 chamfer directions) -> acc[0..3]
__global__ void sqrtsum_kernel(const unsigned* __restrict__ base,
                               int4 offs, int4 cnts, float* __restrict__ acc) {
  const int seg = blockIdx.y;
  const int off = (seg == 0) ? offs.x : (seg == 1) ? offs.y : (seg == 2) ? offs.z : offs.w;
  const int cnt = (seg == 0) ? cnts.x : (seg == 1) ? cnts.y : (seg == 2) ? cnts.z : cnts.w;
  const int i = blockIdx.x * blockDim.x + threadIdx.x;
  float s = 0.f;
  if (i < cnt) s = sqrtf(__uint_as_float(base[off + i]));
  s = wave_reduce_sum(s);
  if ((threadIdx.x & 63) == 0) atomicAdd(&acc[seg], s);
}

__global__ void final_kernel(const float* __restrict__ acc,
                             float* __restrict__ out,
                             int n, int p, int g, int nE) {
  float lt = 0.5f * (acc[0] / (float)n + acc[1] / (float)p);
  float lg = 0.5f * (acc[2] / (float)n + acc[3] / (float)g);
  float chamfer = 0.7f * lt + 0.3f * lg;
  float edge = acc[4] / (float)nE;
  float smooth = acc[5] / (float)n;
  float normal = 1.0f - acc[6] / (float)n;
  out[0] = chamfer + 2.0f * edge + smooth + 0.5f * normal;
}

extern "C" void kernel_launch(void* const* d_in, const int* in_sizes, int n_in,
                              void* d_out, int out_size, void* d_ws, size_t ws_size,
                              hipStream_t stream) {
  const float* sv = (const float*)d_in[0];  // student_verts   (N,3)
  const float* sn = (const float*)d_in[1];  // student_normals (N,3)
  const float* tv = (const float*)d_in[2];  // teacher_verts   (M,3)
  const float* tn = (const float*)d_in[3];  // teacher_normals (M,3)
  const float* tp = (const float*)d_in[4];  // teacher_points  (P,3)
  const float* gp = (const float*)d_in[5];  // gt_points       (G,3)
  const int*   fc = (const int*)d_in[6];    // faces           (F,3)
  const int n = in_sizes[0] / 3;
  const int m = in_sizes[2] / 3;
  const int p = in_sizes[4] / 3;
  const int g = in_sizes[5] / 3;
  const int f = in_sizes[6] / 3;

  // Workspace layout (8-byte aligned region first).
  char* w = (char*)d_ws;
  unsigned long long* min64 = (unsigned long long*)w; w += (size_t)n * 8;
  unsigned* minbase = (unsigned*)w;                   // 4 contiguous arrays
  w += (size_t)(n + p + n + g) * 4;
  float* nbr = (float*)w; w += (size_t)n * 3 * 4;     // zero region starts here
  float* deg = (float*)w; w += (size_t)n * 4;
  float* acc = (float*)w;                             // 8 floats

  unsigned* minA_tp = minbase;
  unsigned* minB_tp = minA_tp + n;
  unsigned* minA_gt = minB_tp + p;
  unsigned* minB_gt = minA_gt + n;

  const int nmin = n + p + n + g;
  const int nz = n * 3 + n + 8;

  init_ws_kernel<<<128, 256, 0, stream>>>(min64, n, minbase, nmin, nbr, nz);

  const int JC = 512;
  dim3 blk(256);
  // chamfer student<->teacher_points
  rowmin_kernel<<<dim3((n + 255) / 256, (p + JC - 1) / JC), blk, 0, stream>>>(sv, n, tp, p, JC, minA_tp);
  rowmin_kernel<<<dim3((p + 255) / 256, (n + JC - 1) / JC), blk, 0, stream>>>(tp, p, sv, n, JC, minB_tp);
  // chamfer student<->gt_points
  rowmin_kernel<<<dim3((n + 255) / 256, (g + JC - 1) / JC), blk, 0, stream>>>(sv, n, gp, g, JC, minA_gt);
  rowmin_kernel<<<dim3((g + 255) / 256, (n + JC - 1) / JC), blk, 0, stream>>>(gp, g, sv, n, JC, minB_gt);
  // nearest teacher vertex (argmin) for normal loss
  rowargmin_kernel<<<dim3((n + 255) / 256, (m + JC - 1) / JC), blk, 0, stream>>>(sv, n, tv, m, JC, min64);

  edge_kernel<<<(3 * f + 255) / 256, blk, 0, stream>>>(fc, f, sv, nbr, deg, acc);
  smooth_kernel<<<(n + 255) / 256, blk, 0, stream>>>(sv, nbr, deg, n, acc);
  normal_kernel<<<(n + 255) / 256, blk, 0, stream>>>(sn, tn, min64, n, acc);

  int4 offs = make_int4(0, n, n + p, n + p + n);
  int4 cnts = make_int4(n, p, n, g);
  int maxc = n > p ? n : p; if (g > maxc) maxc = g;
  sqrtsum_kernel<<<dim3((maxc + 255) / 256, 4), blk, 0, stream>>>(minbase, offs, cnts, acc);

  final_kernel<<<1, 1, 0, stream>>>(acc, (float*)d_out, n, p, g, 3 * f);
}

// Round 2
// 134.899 us; speedup vs baseline: 2.2277x; 2.2277x over previous
//
#include <hip/hip_runtime.h>

// ---------------------------------------------------------------------------
// DistillationLoss, round 2.
// 5 pair passes (4 chamfer directions + 1 argmin) fused into one kernel:
//   - B chunk staged in LDS as float4 (x,y,z,|b|^2)
//   - each thread register-tiles TA=4 rows; 4 VALU ops per pair (3 fma + min)
//   - partial min m = |b|^2 - 2 a.b  (row-constant |a|^2 added at sqrt stage)
//   - m can be negative -> totally-ordered float<->uint flip for atomicMin
// N=M=P=G=8192, F=16384, all fp32. Output: 1 float scalar.
// ---------------------------------------------------------------------------

#define BLK 256   // threads per block
#define TA  4     // rows per thread  (rows per block = 1024)
#define JC  128   // B points per block (y-chunk)

__device__ __forceinline__ float wave_reduce_sum(float v) {
#pragma unroll
  for (int o = 32; o > 0; o >>= 1) v += __shfl_down(v, o, 64);
  return v;
}

// total-order float -> uint (monotone): neg -> ~bits, pos -> bits|0x80000000
__device__ __forceinline__ unsigned flipf(float f) {
  unsigned b = __float_as_uint(f);
  return (b & 0x80000000u) ? ~b : (b | 0x80000000u);
}
__device__ __forceinline__ float unflipf(unsigned u) {
  unsigned b = (u & 0x80000000u) ? (u ^ 0x80000000u) : ~u;
  return __uint_as_float(b);
}

// Workspace init: min64 = ~0 (max), min-bit arrays = flip(+inf)=0xFF800000,
// zero region (nbr, deg, acc).
__global__ void init_ws_kernel(unsigned long long* __restrict__ min64, int n64,
                               unsigned* __restrict__ minbits, int nmin,
                               float* __restrict__ zr, int nz) {
  const int stride = gridDim.x * blockDim.x;
  const int t0 = blockIdx.x * blockDim.x + threadIdx.x;
  for (int i = t0; i < n64; i += stride) min64[i] = ~0ull;
  for (int i = t0; i < nmin; i += stride) minbits[i] = 0xFF800000u;
  for (int i = t0; i < nz; i += stride) zr[i] = 0.0f;
}

struct PassDesc {
  const float* A[5];
  const float* B[5];
  void* out[5];   // unsigned* for passes 0-3 (min), unsigned long long* for 4
};

// blockIdx.z = pass (0..4). pass 4 = argmin. All passes 8192x8192 here.
__global__ void __launch_bounds__(BLK) pairs_kernel(PassDesc pd, int nRows, int nCols) {
  const int pass = blockIdx.z;
  const float* __restrict__ A = pd.A[pass];
  const float* __restrict__ B = pd.B[pass];
  __shared__ float4 sB[JC];

  const int j0 = blockIdx.y * JC;
  const int t = threadIdx.x;
  if (t < JC && j0 + t < nCols) {
    const int j = j0 + t;
    float bx = B[3 * j], by = B[3 * j + 1], bz = B[3 * j + 2];
    sB[t] = make_float4(bx, by, bz, fmaf(bx, bx, fmaf(by, by, bz * bz)));
  }

  const int rowBase = blockIdx.x * (TA * BLK) + t;
  float nax[TA], nay[TA], naz[TA], m[TA];
#pragma unroll
  for (int k = 0; k < TA; ++k) {
    int r = rowBase + k * BLK;
    int rc = (r < nRows) ? r : 0;
    nax[k] = -2.0f * A[3 * rc + 0];
    nay[k] = -2.0f * A[3 * rc + 1];
    naz[k] = -2.0f * A[3 * rc + 2];
    m[k] = __int_as_float(0x7f800000);
  }
  __syncthreads();

  const int jcnt = min(JC, nCols - j0);

  if (pass < 4) {
#pragma unroll 4
    for (int jj = 0; jj < jcnt; ++jj) {
      float4 b = sB[jj];
#pragma unroll
      for (int k = 0; k < TA; ++k)
        m[k] = fminf(m[k], fmaf(nax[k], b.x, fmaf(nay[k], b.y, fmaf(naz[k], b.z, b.w))));
    }
    unsigned* __restrict__ out = (unsigned*)pd.out[pass];
#pragma unroll
    for (int k = 0; k < TA; ++k) {
      int r = rowBase + k * BLK;
      if (r < nRows) atomicMin(out + r, flipf(m[k]));
    }
  } else {
    int idx[TA];
#pragma unroll
    for (int k = 0; k < TA; ++k) idx[k] = j0;
#pragma unroll 4
    for (int jj = 0; jj < jcnt; ++jj) {
      float4 b = sB[jj];
#pragma unroll
      for (int k = 0; k < TA; ++k) {
        float d = fmaf(nax[k], b.x, fmaf(nay[k], b.y, fmaf(naz[k], b.z, b.w)));
        if (d < m[k]) { m[k] = d; idx[k] = j0 + jj; }
      }
    }
    unsigned long long* __restrict__ out = (unsigned long long*)pd.out[pass];
#pragma unroll
    for (int k = 0; k < TA; ++k) {
      int r = rowBase + k * BLK;
      unsigned long long packed =
          ((unsigned long long)flipf(m[k]) << 32) | (unsigned)idx[k];
      if (r < nRows) atomicMin(out + r, packed);
    }
  }
}

// One thread per edge (3F edges). sum(edge_len^2) -> acc[4]; laplacian sums.
__global__ void edge_kernel(const int* __restrict__ fc, int f,
                            const float* __restrict__ v,
                            float* __restrict__ nbr, float* __restrict__ deg,
                            float* __restrict__ acc) {
  const int e = blockIdx.x * blockDim.x + threadIdx.x;
  const int nE = 3 * f;
  float es = 0.f;
  if (e < nE) {
    int a, b;
    if (e < f) { a = fc[3 * e + 0]; b = fc[3 * e + 1]; }
    else if (e < 2 * f) { int tt = e - f; a = fc[3 * tt + 1]; b = fc[3 * tt + 2]; }
    else { int tt = e - 2 * f; a = fc[3 * tt + 2]; b = fc[3 * tt + 0]; }
    float axv = v[3 * a], ayv = v[3 * a + 1], azv = v[3 * a + 2];
    float bxv = v[3 * b], byv = v[3 * b + 1], bzv = v[3 * b + 2];
    float dx = axv - bxv, dy = ayv - byv, dz = azv - bzv;
    es = fmaf(dx, dx, fmaf(dy, dy, dz * dz));
    atomicAdd(&nbr[3 * a + 0], bxv);
    atomicAdd(&nbr[3 * a + 1], byv);
    atomicAdd(&nbr[3 * a + 2], bzv);
    atomicAdd(&nbr[3 * b + 0], axv);
    atomicAdd(&nbr[3 * b + 1], ayv);
    atomicAdd(&nbr[3 * b + 2], azv);
    atomicAdd(&deg[a], 1.0f);
    atomicAdd(&deg[b], 1.0f);
  }
  es = wave_reduce_sum(es);
  if ((threadIdx.x & 63) == 0) atomicAdd(&acc[4], es);
}

// Fused tail: blockIdx.y selects task.
// y=0: laplacian smooth -> acc[5]; y=1: normal cosine -> acc[6]
// y=2..5: chamfer sqrt-sums (seg = y-2) -> acc[seg]
__global__ void post_kernel(const float* __restrict__ sv,
                            const float* __restrict__ sn,
                            const float* __restrict__ tn,
                            const float* __restrict__ tp,
                            const float* __restrict__ gp,
                            const float* __restrict__ nbr,
                            const float* __restrict__ deg,
                            const unsigned* __restrict__ minbase,
                            const unsigned long long* __restrict__ min64,
                            int n, int p, float* __restrict__ acc) {
  const int task = blockIdx.y;
  const int i = blockIdx.x * blockDim.x + threadIdx.x;
  float s = 0.f;
  int accIdx;
  if (task == 0) {
    accIdx = 5;
    if (i < n) {
      float d = fmaxf(deg[i], 1.0f);
      float lx = nbr[3 * i + 0] / d - sv[3 * i + 0];
      float ly = nbr[3 * i + 1] / d - sv[3 * i + 1];
      float lz = nbr[3 * i + 2] / d - sv[3 * i + 2];
      s = sqrtf(fmaf(lx, lx, fmaf(ly, ly, lz * lz)));
    }
  } else if (task == 1) {
    accIdx = 6;
    if (i < n) {
      int idx = (int)(min64[i] & 0xffffffffull);
      float sx = sn[3 * i], sy = sn[3 * i + 1], sz = sn[3 * i + 2];
      float tx = tn[3 * idx], ty = tn[3 * idx + 1], tz = tn[3 * idx + 2];
      float num = fmaf(sx, tx, fmaf(sy, ty, sz * tz));
      float ns = sqrtf(fmaf(sx, sx, fmaf(sy, sy, sz * sz)));
      float nt = sqrtf(fmaf(tx, tx, fmaf(ty, ty, tz * tz)));
      s = num / (fmaxf(ns, 1e-8f) * fmaxf(nt, 1e-8f));
    }
  } else {
    const int seg = task - 2;
    accIdx = seg;
    // seg rows: 0 -> sv (cnt n), 1 -> tp (cnt p), 2 -> sv (n), 3 -> gp (n)
    const float* Aarr = (seg == 1) ? tp : (seg == 3) ? gp : sv;
    const int off = (seg == 0) ? 0 : (seg == 1) ? n : (seg == 2) ? (n + p) : (2 * n + p);
    const int cnt = (seg == 1) ? p : n;
    if (i < cnt) {
      float mval = unflipf(minbase[off + i]);
      float ax = Aarr[3 * i], ay = Aarr[3 * i + 1], az = Aarr[3 * i + 2];
      float aa = fmaf(ax, ax, fmaf(ay, ay, az * az));
      s = sqrtf(fmaxf(mval + aa, 0.0f));
    }
  }
  s = wave_reduce_sum(s);
  if ((threadIdx.x & 63) == 0) atomicAdd(&acc[accIdx], s);
}

__global__ void final_kernel(const float* __restrict__ acc,
                             float* __restrict__ out,
                             int n, int p, int g, int nE) {
  float lt = 0.5f * (acc[0] / (float)n + acc[1] / (float)p);
  float lg = 0.5f * (acc[2] / (float)n + acc[3] / (float)g);
  float chamfer = 0.7f * lt + 0.3f * lg;
  float edge = acc[4] / (float)nE;
  float smooth = acc[5] / (float)n;
  float normal = 1.0f - acc[6] / (float)n;
  out[0] = chamfer + 2.0f * edge + smooth + 0.5f * normal;
}

extern "C" void kernel_launch(void* const* d_in, const int* in_sizes, int n_in,
                              void* d_out, int out_size, void* d_ws, size_t ws_size,
                              hipStream_t stream) {
  const float* sv = (const float*)d_in[0];  // student_verts   (N,3)
  const float* sn = (const float*)d_in[1];  // student_normals (N,3)
  const float* tv = (const float*)d_in[2];  // teacher_verts   (M,3)
  const float* tn = (const float*)d_in[3];  // teacher_normals (M,3)
  const float* tp = (const float*)d_in[4];  // teacher_points  (P,3)
  const float* gp = (const float*)d_in[5];  // gt_points       (G,3)
  const int*   fc = (const int*)d_in[6];    // faces           (F,3)
  const int n = in_sizes[0] / 3;
  const int m = in_sizes[2] / 3;
  const int p = in_sizes[4] / 3;
  const int g = in_sizes[5] / 3;
  const int f = in_sizes[6] / 3;

  // Workspace layout (8-byte aligned region first). ~320 KB total.
  char* w = (char*)d_ws;
  unsigned long long* min64 = (unsigned long long*)w; w += (size_t)n * 8;
  unsigned* minbase = (unsigned*)w;                   // 4 contiguous min arrays
  w += (size_t)(n + p + n + g) * 4;
  float* nbr = (float*)w; w += (size_t)n * 3 * 4;     // zero region starts here
  float* deg = (float*)w; w += (size_t)n * 4;
  float* acc = (float*)w;                             // 8 floats

  unsigned* minA_tp = minbase;
  unsigned* minB_tp = minA_tp + n;
  unsigned* minA_gt = minB_tp + p;
  unsigned* minB_gt = minA_gt + n;

  const int nmin = n + p + n + g;
  const int nz = n * 3 + n + 8;

  init_ws_kernel<<<128, BLK, 0, stream>>>(min64, n, minbase, nmin, nbr, nz);

  PassDesc pd;
  pd.A[0] = sv; pd.B[0] = tp; pd.out[0] = minA_tp;  // min_j |sv_i - tp_j|
  pd.A[1] = tp; pd.B[1] = sv; pd.out[1] = minB_tp;
  pd.A[2] = sv; pd.B[2] = gp; pd.out[2] = minA_gt;
  pd.A[3] = gp; pd.B[3] = sv; pd.out[3] = minB_gt;
  pd.A[4] = sv; pd.B[4] = tv; pd.out[4] = min64;    // argmin over teacher verts

  // All five passes are 8192x8192 (n=m=p=g). Grid: 8 x 64 x 5 = 2560 blocks.
  dim3 pgrid((n + TA * BLK - 1) / (TA * BLK), (n + JC - 1) / JC, 5);
  pairs_kernel<<<pgrid, BLK, 0, stream>>>(pd, n, n);

  edge_kernel<<<(3 * f + BLK - 1) / BLK, BLK, 0, stream>>>(fc, f, sv, nbr, deg, acc);

  dim3 tgrid((n + BLK - 1) / BLK, 6);
  post_kernel<<<tgrid, BLK, 0, stream>>>(sv, sn, tn, tp, gp, nbr, deg,
                                         minbase, min64, n, p, acc);

  final_kernel<<<1, 1, 0, stream>>>(acc, (float*)d_out, n, p, g, 3 * f);
}

// Round 3
// 129.210 us; speedup vs baseline: 2.3257x; 1.0440x over previous
//
#include <hip/hip_runtime.h>

// ---------------------------------------------------------------------------
// DistillationLoss, round 3.
// 3 launches: init_ws -> mega (5 pair passes + edge pass, blockIdx.z) -> post
// Pair passes: B chunk (JC=256 pts) staged in LDS as SoA f32x4 (x4,y4,z4,w4);
// each thread owns TA=8 rows; packed-fp32 math (v_pk_fma_f32 via
// __builtin_elementwise_fma on float2): 2.5 VALU slots/pair.
// partial min m = |b|^2 - 2 a.b  (row |a|^2 added at sqrt stage).
// post fuses smooth/normal/4 sqrt-sums + last-block final reduction.
// ---------------------------------------------------------------------------

typedef float f32x2 __attribute__((ext_vector_type(2)));
typedef float f32x4 __attribute__((ext_vector_type(4)));

#define BLK 256
#define TA 8                      // rows per thread -> 2048 rows per block
#define JC 256                    // B points per y-chunk

__device__ __forceinline__ float wave_reduce_sum(float v) {
#pragma unroll
  for (int o = 32; o > 0; o >>= 1) v += __shfl_down(v, o, 64);
  return v;
}

// total-order float -> uint (monotone)
__device__ __forceinline__ unsigned flipf(float f) {
  unsigned b = __float_as_uint(f);
  return (b & 0x80000000u) ? ~b : (b | 0x80000000u);
}
__device__ __forceinline__ float unflipf(unsigned u) {
  unsigned b = (u & 0x80000000u) ? (u ^ 0x80000000u) : ~u;
  return __uint_as_float(b);
}

__device__ __forceinline__ f32x2 splat2(float v) {
  f32x2 r; r.x = v; r.y = v; return r;
}

__global__ void init_ws_kernel(unsigned long long* __restrict__ min64, int n64,
                               unsigned* __restrict__ minbits, int nmin,
                               float* __restrict__ zr, int nz) {
  const int stride = gridDim.x * blockDim.x;
  const int t0 = blockIdx.x * blockDim.x + threadIdx.x;
  for (int i = t0; i < n64; i += stride) min64[i] = ~0ull;
  for (int i = t0; i < nmin; i += stride) minbits[i] = 0xFF800000u;  // flip(+inf)
  for (int i = t0; i < nz; i += stride) zr[i] = 0.0f;                // also cnt=0
}

struct Desc {
  const float* A[5];
  const float* B[5];
  void* out[5];          // unsigned* for 0-3, unsigned long long* for 4
  const int* fc; int f;
  const float* sv;
  float* nbr; float* deg; float* acc;
  int nRows, nCols;
};

// blockIdx.z: 0-3 chamfer min passes, 4 argmin pass, 5 edge pass.
__global__ void __launch_bounds__(BLK) mega_kernel(Desc d) {
  const int pass = blockIdx.z;
  const int t = threadIdx.x;

  if (pass == 5) {
    // ---- edge + laplacian accumulation ----
    const int nE = 3 * d.f;
    const int bid = blockIdx.y * gridDim.x + blockIdx.x;
    const int stride = gridDim.x * gridDim.y * BLK;
    float es = 0.f;
    for (int e = bid * BLK + t; e < nE; e += stride) {
      int a, b;
      if (e < d.f)            { a = d.fc[3 * e + 0];  b = d.fc[3 * e + 1]; }
      else if (e < 2 * d.f)   { int q = e - d.f;     a = d.fc[3 * q + 1]; b = d.fc[3 * q + 2]; }
      else                    { int q = e - 2 * d.f; a = d.fc[3 * q + 2]; b = d.fc[3 * q + 0]; }
      float ax = d.sv[3 * a], ay = d.sv[3 * a + 1], az = d.sv[3 * a + 2];
      float bx = d.sv[3 * b], by = d.sv[3 * b + 1], bz = d.sv[3 * b + 2];
      float dx = ax - bx, dy = ay - by, dz = az - bz;
      es += fmaf(dx, dx, fmaf(dy, dy, dz * dz));
      atomicAdd(&d.nbr[3 * a + 0], bx);
      atomicAdd(&d.nbr[3 * a + 1], by);
      atomicAdd(&d.nbr[3 * a + 2], bz);
      atomicAdd(&d.nbr[3 * b + 0], ax);
      atomicAdd(&d.nbr[3 * b + 1], ay);
      atomicAdd(&d.nbr[3 * b + 2], az);
      atomicAdd(&d.deg[a], 1.0f);
      atomicAdd(&d.deg[b], 1.0f);
    }
    es = wave_reduce_sum(es);
    if ((t & 63) == 0) atomicAdd(&d.acc[4], es);
    return;
  }

  // ---- pair pass ----
  __shared__ f32x4 sX[JC / 4], sY[JC / 4], sZ[JC / 4], sW[JC / 4];
  const float* __restrict__ A = d.A[pass];
  const float* __restrict__ B = d.B[pass];
  const int j0 = blockIdx.y * JC;
  {
    int j = j0 + t;
    float bx = 0.f, by = 0.f, bz = 0.f, bw = 1e30f;
    if (j < d.nCols) {
      bx = B[3 * j]; by = B[3 * j + 1]; bz = B[3 * j + 2];
      bw = fmaf(bx, bx, fmaf(by, by, bz * bz));
    }
    ((float*)sX)[t] = bx; ((float*)sY)[t] = by;
    ((float*)sZ)[t] = bz; ((float*)sW)[t] = bw;
  }

  const int rowBase = blockIdx.x * (TA * BLK) + t;
  f32x2 nax[TA], nay[TA], naz[TA], m2[TA];
#pragma unroll
  for (int k = 0; k < TA; ++k) {
    int r = rowBase + k * BLK;
    int rc = (r < d.nRows) ? r : 0;
    nax[k] = splat2(-2.0f * A[3 * rc + 0]);
    nay[k] = splat2(-2.0f * A[3 * rc + 1]);
    naz[k] = splat2(-2.0f * A[3 * rc + 2]);
    m2[k] = splat2(1e30f);
  }
  __syncthreads();

  if (pass < 4) {
#pragma unroll 2
    for (int jg = 0; jg < JC / 4; ++jg) {
      f32x4 X = sX[jg], Y = sY[jg], Z = sZ[jg], W = sW[jg];
      f32x2 x01 = X.xy, x23 = X.zw;
      f32x2 y01 = Y.xy, y23 = Y.zw;
      f32x2 z01 = Z.xy, z23 = Z.zw;
      f32x2 w01 = W.xy, w23 = W.zw;
#pragma unroll
      for (int k = 0; k < TA; ++k) {
        f32x2 d01 = __builtin_elementwise_fma(naz[k], z01, w01);
        d01 = __builtin_elementwise_fma(nay[k], y01, d01);
        d01 = __builtin_elementwise_fma(nax[k], x01, d01);
        f32x2 d23 = __builtin_elementwise_fma(naz[k], z23, w23);
        d23 = __builtin_elementwise_fma(nay[k], y23, d23);
        d23 = __builtin_elementwise_fma(nax[k], x23, d23);
        f32x2 dm = __builtin_elementwise_min(d01, d23);
        m2[k] = __builtin_elementwise_min(m2[k], dm);
      }
    }
    unsigned* __restrict__ out = (unsigned*)d.out[pass];
#pragma unroll
    for (int k = 0; k < TA; ++k) {
      int r = rowBase + k * BLK;
      if (r < d.nRows) atomicMin(out + r, flipf(fminf(m2[k].x, m2[k].y)));
    }
  } else {
    // argmin pass: track index as float (j < 2^24 exact)
    f32x2 id2[TA];
#pragma unroll
    for (int k = 0; k < TA; ++k) id2[k] = splat2(0.f);
#pragma unroll 2
    for (int jg = 0; jg < JC / 4; ++jg) {
      f32x4 X = sX[jg], Y = sY[jg], Z = sZ[jg], W = sW[jg];
      f32x2 x01 = X.xy, x23 = X.zw;
      f32x2 y01 = Y.xy, y23 = Y.zw;
      f32x2 z01 = Z.xy, z23 = Z.zw;
      f32x2 w01 = W.xy, w23 = W.zw;
      float jb = (float)(j0 + 4 * jg);
      float j1f = jb + 1.f, j2f = jb + 2.f, j3f = jb + 3.f;
#pragma unroll
      for (int k = 0; k < TA; ++k) {
        f32x2 d01 = __builtin_elementwise_fma(naz[k], z01, w01);
        d01 = __builtin_elementwise_fma(nay[k], y01, d01);
        d01 = __builtin_elementwise_fma(nax[k], x01, d01);
        f32x2 d23 = __builtin_elementwise_fma(naz[k], z23, w23);
        d23 = __builtin_elementwise_fma(nay[k], y23, d23);
        d23 = __builtin_elementwise_fma(nax[k], x23, d23);
        bool c0 = d01.x < m2[k].x;
        m2[k].x = c0 ? d01.x : m2[k].x;  id2[k].x = c0 ? jb  : id2[k].x;
        bool c1 = d01.y < m2[k].y;
        m2[k].y = c1 ? d01.y : m2[k].y;  id2[k].y = c1 ? j1f : id2[k].y;
        bool c2 = d23.x < m2[k].x;
        m2[k].x = c2 ? d23.x : m2[k].x;  id2[k].x = c2 ? j2f : id2[k].x;
        bool c3 = d23.y < m2[k].y;
        m2[k].y = c3 ? d23.y : m2[k].y;  id2[k].y = c3 ? j3f : id2[k].y;
      }
    }
    unsigned long long* __restrict__ out = (unsigned long long*)d.out[4];
#pragma unroll
    for (int k = 0; k < TA; ++k) {
      int r = rowBase + k * BLK;
      unsigned long long pa =
          ((unsigned long long)flipf(m2[k].x) << 32) | (unsigned)(int)id2[k].x;
      unsigned long long pb =
          ((unsigned long long)flipf(m2[k].y) << 32) | (unsigned)(int)id2[k].y;
      unsigned long long best = pa < pb ? pa : pb;
      if (r < d.nRows) atomicMin(out + r, best);
    }
  }
}

// Fused tail. blockIdx.y: 0 smooth->acc[5], 1 normal->acc[6], 2-5 sqrt-sums
// ->acc[0..3]. Last block (ticket) computes the final scalar.
__global__ void __launch_bounds__(BLK) post_kernel(
    const float* __restrict__ sv, const float* __restrict__ sn,
    const float* __restrict__ tn, const float* __restrict__ tp,
    const float* __restrict__ gp, const float* __restrict__ nbr,
    const float* __restrict__ deg, const unsigned* __restrict__ minbase,
    const unsigned long long* __restrict__ min64,
    int n, int p, int g, int f, float* __restrict__ acc,
    int* __restrict__ cnt, float* __restrict__ out) {
  const int task = blockIdx.y;
  const int i = blockIdx.x * blockDim.x + threadIdx.x;
  float s = 0.f;
  int accIdx;
  if (task == 0) {
    accIdx = 5;
    if (i < n) {
      float dd = fmaxf(deg[i], 1.0f);
      float lx = nbr[3 * i + 0] / dd - sv[3 * i + 0];
      float ly = nbr[3 * i + 1] / dd - sv[3 * i + 1];
      float lz = nbr[3 * i + 2] / dd - sv[3 * i + 2];
      s = sqrtf(fmaf(lx, lx, fmaf(ly, ly, lz * lz)));
    }
  } else if (task == 1) {
    accIdx = 6;
    if (i < n) {
      int idx = (int)(min64[i] & 0xffffffffull);
      float sx = sn[3 * i], sy = sn[3 * i + 1], sz = sn[3 * i + 2];
      float tx = tn[3 * idx], ty = tn[3 * idx + 1], tz = tn[3 * idx + 2];
      float num = fmaf(sx, tx, fmaf(sy, ty, sz * tz));
      float ns = sqrtf(fmaf(sx, sx, fmaf(sy, sy, sz * sz)));
      float nt = sqrtf(fmaf(tx, tx, fmaf(ty, ty, tz * tz)));
      s = num / (fmaxf(ns, 1e-8f) * fmaxf(nt, 1e-8f));
    }
  } else {
    const int seg = task - 2;
    accIdx = seg;
    const float* Aarr = (seg == 1) ? tp : (seg == 3) ? gp : sv;
    const int off = (seg == 0) ? 0 : (seg == 1) ? n : (seg == 2) ? (n + p) : (2 * n + p);
    const int cntN = (seg == 1) ? p : n;
    if (i < cntN) {
      float mval = unflipf(minbase[off + i]);
      float ax = Aarr[3 * i], ay = Aarr[3 * i + 1], az = Aarr[3 * i + 2];
      float aa = fmaf(ax, ax, fmaf(ay, ay, az * az));
      s = sqrtf(fmaxf(mval + aa, 0.0f));
    }
  }
  s = wave_reduce_sum(s);
  if ((threadIdx.x & 63) == 0) atomicAdd(&acc[accIdx], s);

  __syncthreads();
  __threadfence();
  __shared__ int last;
  if (threadIdx.x == 0)
    last = (atomicAdd(cnt, 1) == (int)(gridDim.x * gridDim.y) - 1);
  __syncthreads();
  if (last && threadIdx.x == 0) {
    float a[7];
#pragma unroll
    for (int q = 0; q < 7; ++q) a[q] = atomicAdd(&acc[q], 0.0f);
    float lt = 0.5f * (a[0] / (float)n + a[1] / (float)p);
    float lg = 0.5f * (a[2] / (float)n + a[3] / (float)g);
    float chamfer = 0.7f * lt + 0.3f * lg;
    float edge = a[4] / (float)(3 * f);
    float smooth = a[5] / (float)n;
    float normal = 1.0f - a[6] / (float)n;
    out[0] = chamfer + 2.0f * edge + smooth + 0.5f * normal;
  }
}

extern "C" void kernel_launch(void* const* d_in, const int* in_sizes, int n_in,
                              void* d_out, int out_size, void* d_ws, size_t ws_size,
                              hipStream_t stream) {
  const float* sv = (const float*)d_in[0];
  const float* sn = (const float*)d_in[1];
  const float* tv = (const float*)d_in[2];
  const float* tn = (const float*)d_in[3];
  const float* tp = (const float*)d_in[4];
  const float* gp = (const float*)d_in[5];
  const int*   fc = (const int*)d_in[6];
  const int n = in_sizes[0] / 3;
  const int m = in_sizes[2] / 3;
  const int p = in_sizes[4] / 3;
  const int g = in_sizes[5] / 3;
  const int f = in_sizes[6] / 3;

  // ws layout
  char* w = (char*)d_ws;
  unsigned long long* min64 = (unsigned long long*)w; w += (size_t)n * 8;
  unsigned* minbase = (unsigned*)w; w += (size_t)(n + p + n + g) * 4;
  float* nbr = (float*)w; w += (size_t)n * 3 * 4;   // zero region starts here
  float* deg = (float*)w; w += (size_t)n * 4;
  float* acc = (float*)w; w += 8 * 4;
  int* cnt = (int*)w;

  unsigned* minA_tp = minbase;
  unsigned* minB_tp = minA_tp + n;
  unsigned* minA_gt = minB_tp + p;
  unsigned* minB_gt = minA_gt + n;

  const int nmin = n + p + n + g;
  const int nz = n * 3 + n + 8 + 1;   // nbr, deg, acc, cnt

  init_ws_kernel<<<64, BLK, 0, stream>>>(min64, n, minbase, nmin, nbr, nz);

  Desc d;
  d.A[0] = sv; d.B[0] = tp; d.out[0] = minA_tp;
  d.A[1] = tp; d.B[1] = sv; d.out[1] = minB_tp;
  d.A[2] = sv; d.B[2] = gp; d.out[2] = minA_gt;
  d.A[3] = gp; d.B[3] = sv; d.out[3] = minB_gt;
  d.A[4] = sv; d.B[4] = tv; d.out[4] = min64;
  d.fc = fc; d.f = f; d.sv = sv;
  d.nbr = nbr; d.deg = deg; d.acc = acc;
  d.nRows = n; d.nCols = n;  // all passes 8192x8192

  dim3 pgrid((n + TA * BLK - 1) / (TA * BLK), (n + JC - 1) / JC, 6);
  mega_kernel<<<pgrid, BLK, 0, stream>>>(d);

  dim3 tgrid((n + BLK - 1) / BLK, 6);
  post_kernel<<<tgrid, BLK, 0, stream>>>(sv, sn, tn, tp, gp, nbr, deg,
                                         minbase, min64, n, p, g, f,
                                         acc, cnt, (float*)d_out);
}